// Round 9
// baseline (1358.269 us; speedup 1.0000x reference)
//
#include <hip/hip_runtime.h>
#include <math.h>

// Problem constants (fixed by setup_inputs)
#define BATCH 4
#define CCH   256   // channels
#define DQK   32    // q/k channels
#define NPIX  4096  // H*W
#define LOG2E 1.44269504088896340736f

typedef __attribute__((ext_vector_type(8)))  short          short8_t;
typedef __attribute__((ext_vector_type(4)))  unsigned short ushort4_t;
typedef __attribute__((ext_vector_type(8)))  unsigned short ushort8_t;
typedef __attribute__((ext_vector_type(16))) float          f32x16;
typedef __attribute__((ext_vector_type(2)))  unsigned int   uint2_t;

#if __has_builtin(__builtin_amdgcn_exp2f)
#define EXP2F(x) __builtin_amdgcn_exp2f(x)
#else
#define EXP2F(x) exp2f(x)
#endif

#define MFMA32(a, b, c) __builtin_amdgcn_mfma_f32_32x32x16_bf16(a, b, c, 0, 0, 0)

static __device__ __forceinline__ unsigned short f2bf(float f) {
    union { float f; unsigned int u; } v; v.f = f;
    unsigned int r = v.u + 0x7FFFu + ((v.u >> 16) & 1u);   // RNE
    return (unsigned short)(r >> 16);
}

static __device__ __forceinline__ short8_t cat8(ushort4_t a, ushort4_t b) {
    ushort8_t c = __builtin_shufflevector(a, b, 0, 1, 2, 3, 4, 5, 6, 7);
    short8_t r; __builtin_memcpy(&r, &c, 16); return r;
}

static __device__ __forceinline__ short8_t u4_to_s8(const unsigned int* u) {
    short8_t r; __builtin_memcpy(&r, u, 16); return r;
}

// permlane32_swap(a,b) -> {x = {a_lo32lanes, b_lo32lanes}, y = {a_hi, b_hi}}
static __device__ __forceinline__ uint2_t plswap(unsigned int a, unsigned int b) {
#if __has_builtin(__builtin_amdgcn_permlane32_swap)
    return __builtin_amdgcn_permlane32_swap(a, b, false, false);
#else
    const unsigned int sa = (unsigned int)__shfl_xor((int)a, 32);
    const unsigned int sb = (unsigned int)__shfl_xor((int)b, 32);
    const int h = (threadIdx.x >> 5) & 1;
    uint2_t r;
    r.x = h ? sb : a;
    r.y = h ? b : sa;
    return r;
#endif
}

// S (C-layout) -> exp2 -> packed bf16 PV B-operand fragments; accumulates l
static __device__ __forceinline__ void make_bfrag(
    const f32x16& s, float& l0, float& l1, unsigned int bfr[2][4])
{
    float pv[16];
    #pragma unroll
    for (int r = 0; r < 16; ++r) pv[r] = EXP2F(s[r]);
    #pragma unroll
    for (int r = 0; r < 16; r += 2) { l0 += pv[r]; l1 += pv[r + 1]; }
    unsigned int P[8];
    #pragma unroll
    for (int v = 0; v < 8; ++v)
        P[v] = __builtin_amdgcn_perm(__float_as_uint(pv[2 * v + 1]),
                                     __float_as_uint(pv[2 * v]), 0x07060302u);
    #pragma unroll
    for (int kp = 0; kp < 2; ++kp) {
        const uint2_t r02 = plswap(P[4 * kp + 0], P[4 * kp + 2]);
        const uint2_t r13 = plswap(P[4 * kp + 1], P[4 * kp + 3]);
        bfr[kp][0] = r02.x; bfr[kp][1] = r13.x;
        bfr[kp][2] = r02.y; bfr[kp][3] = r13.y;
    }
}

// ---------------------------------------------------------------------------
// Stage 0 (fused): blocks 0..319 convert weights to A-frag layout
//   wbf[((c>>3)*320 + o)*8 + (c&7)] (o: 0-31 Wq x log2e, 32-63 Wk, 64-319 Wv);
// blocks 320..831 transpose x (fp32 [b][c][n]) -> bf16 B-fragment layout
//   xfrag[(((b*128 + nt)*32 + slot)*32 + il)*8 + e], c = slot*8+e, n = nt*32+il
// ---------------------------------------------------------------------------
__global__ __launch_bounds__(256) void prep_kernel(
    const float* __restrict__ Wq, const float* __restrict__ Wk,
    const float* __restrict__ Wv, const float* __restrict__ x,
    unsigned short* __restrict__ wbf, unsigned short* __restrict__ xfrag)
{
    const int t = threadIdx.x;
    if (blockIdx.x < 320) {
        const int idx = blockIdx.x * 256 + t;
        const int o = idx >> 8, c = idx & 255;
        float v;
        if (o < 32)      v = Wq[o * 256 + c] * LOG2E;
        else if (o < 64) v = Wk[(o - 32) * 256 + c];
        else             v = Wv[(o - 64) * 256 + c];
        wbf[((c >> 3) * 320 + o) * 8 + (c & 7)] = f2bf(v);
        return;
    }
    const int bid = blockIdx.x - 320;        // 0..511
    const int b = bid >> 7, cg8 = (bid >> 4) & 7, ng = bid & 15;
    const int w = t >> 6, l = t & 63;

    float f[4][8];
    #pragma unroll
    for (int p = 0; p < 8; ++p) {
        const float* row = x + ((size_t)(b * CCH + cg8 * 32 + w * 8 + p)) * NPIX
                             + ng * 256;
        #pragma unroll
        for (int j = 0; j < 4; ++j)
            f[j][p] = row[j * 64 + l];
    }
    #pragma unroll
    for (int j = 0; j < 4; ++j) {
        unsigned int d[4];
        #pragma unroll
        for (int k = 0; k < 4; ++k)
            d[k] = __builtin_amdgcn_perm(__float_as_uint(f[j][2 * k + 1]),
                                         __float_as_uint(f[j][2 * k]), 0x07060302u);
        const int nt = ng * 8 + j * 2 + (l >> 5);
        unsigned short* dst = xfrag +
            ((((size_t)(b * 128 + nt) * 32) + cg8 * 4 + w) * 32 + (l & 31)) * 8;
        *(short8_t*)dst = u4_to_s8(d);
    }
}

// ---------------------------------------------------------------------------
// Stage 1: LDS-free MFMA projections. D[o=320][n] = W[o][c] * x[c][n].
// Block = (b, 32-n tile), grid 512, 320 thr = 5 waves (wave w: o = 64w..).
// K-loop: coalesced W A-frags + xfrag B-frags; no barriers anywhere.
// Epilogue: per-wave LDS transpose into fragment layouts:
//   qfrag/kfrag[(((b*128+nt)*4 + dslot)*32 + n)*8], vfrag[(((b*128+nt)*4+jslot)*256+c)*8]
// ---------------------------------------------------------------------------
__global__ __launch_bounds__(320) void proj_kernel(
    const unsigned short* __restrict__ xfrag, const unsigned short* __restrict__ wbf,
    const float* __restrict__ bq, const float* __restrict__ bk,
    const float* __restrict__ bv,
    unsigned short* __restrict__ qfrag, unsigned short* __restrict__ kfrag,
    unsigned short* __restrict__ vfrag)
{
    __shared__ unsigned short qkb[2 * 32 * 40];    // [q/k][n 32][d 32 pad 40]
    __shared__ unsigned short vbuf[4 * 64 * 40];   // per v-wave [c 64][n 32 pad 40]

    const int b  = blockIdx.x >> 7;
    const int nt = blockIdx.x & 127;
    const int t  = threadIdx.x;
    const int w = t >> 6, lane = t & 63, il = lane & 31, h = lane >> 5;

    // bias prefetch (lane needs base + 8g + 4h + 0..3 for g = r>>2)
    float4 bA[4], bB[4];
    #pragma unroll
    for (int g = 0; g < 4; ++g) {
        if (w == 0) {
            bA[g] = *(const float4*)&bq[8 * g + 4 * h];
            bB[g] = *(const float4*)&bk[8 * g + 4 * h];
        } else {
            bA[g] = *(const float4*)&bv[(w - 1) * 64 + 8 * g + 4 * h];
            bB[g] = *(const float4*)&bv[(w - 1) * 64 + 32 + 8 * g + 4 * h];
        }
    }

    f32x16 acc0, acc1;   // o-halves (w*64.. / w*64+32..)
    #pragma unroll
    for (int r = 0; r < 16; ++r) { acc0[r] = 0.f; acc1[r] = 0.f; }

    const unsigned short* wp = wbf + ((size_t)(h * 320 + w * 64 + il)) * 8;
    const unsigned short* xp = xfrag + (((size_t)(b * 128 + nt) * 32 + h) * 32 + il) * 8;

    #pragma unroll 4
    for (int ks = 0; ks < 16; ++ks) {
        const short8_t af0 = *(const short8_t*)(wp + ks * 5120);
        const short8_t af1 = *(const short8_t*)(wp + ks * 5120 + 256);
        const short8_t bfr = *(const short8_t*)(xp + (size_t)ks * 512);
        acc0 = MFMA32(af0, bfr, acc0);
        acc1 = MFMA32(af1, bfr, acc1);
    }

    // ---- epilogue (same-wave LDS transposes only; zero barriers) ----
    if (w == 0) {
        #pragma unroll
        for (int r = 0; r < 16; ++r) {
            const int d = (r & 3) + 8 * (r >> 2) + 4 * h;
            qkb[il * 40 + d]        = f2bf(acc0[r] + bA[r >> 2][r & 3] * LOG2E);
            qkb[1280 + il * 40 + d] = f2bf(acc1[r] + bB[r >> 2][r & 3]);
        }
        #pragma unroll
        for (int rep = 0; rep < 2; ++rep) {
            const int u = rep * 64 + lane;       // 128 chunks: slot(4) x n(32)
            const int slot = u >> 5, n = u & 31;
            ushort4_t qlo = *(const ushort4_t*)&qkb[n * 40 + slot * 8];
            ushort4_t qhi = *(const ushort4_t*)&qkb[n * 40 + slot * 8 + 4];
            ushort4_t klo = *(const ushort4_t*)&qkb[1280 + n * 40 + slot * 8];
            ushort4_t khi = *(const ushort4_t*)&qkb[1280 + n * 40 + slot * 8 + 4];
            const size_t o8 = (((size_t)(b * 128 + nt) * 4 + slot) * 32 + n) * 8;
            *(short8_t*)(qfrag + o8) = cat8(qlo, qhi);
            *(short8_t*)(kfrag + o8) = cat8(klo, khi);
        }
    } else {
        unsigned short* vb = vbuf + (w - 1) * 64 * 40;   // [c 64][n 32 pad 40]
        #pragma unroll
        for (int r = 0; r < 16; ++r) {
            const int orow = (r & 3) + 8 * (r >> 2) + 4 * h;
            vb[(orow)      * 40 + il] = f2bf(acc0[r] + bA[r >> 2][r & 3]);
            vb[(orow + 32) * 40 + il] = f2bf(acc1[r] + bB[r >> 2][r & 3]);
        }
        #pragma unroll
        for (int slot = 0; slot < 4; ++slot) {   // 4 reps: slot x c(64 = lane)
            ushort4_t lo = *(const ushort4_t*)&vb[lane * 40 + slot * 8];
            ushort4_t hi = *(const ushort4_t*)&vb[lane * 40 + slot * 8 + 4];
            const size_t o8 = (((size_t)(b * 128 + nt) * 4 + slot) * 256 +
                               (w - 1) * 64 + lane) * 8;
            *(short8_t*)(vfrag + o8) = cat8(lo, hi);
        }
    }
}

// ---------------------------------------------------------------------------
// Stage 2: MFMA flash attention — zero LDS/barriers in the main loop.
// Block = (b, 64-query tile), 1024 thr = 16 waves (ci = w&3 channel quarter,
// jj = w>>2 j-quarter of 32 tiles). 4 waves/SIMD at grid 256 (1 block/CU).
// p = exp2(s) un-normalized => disjoint-j partials add linearly; end combine
// is a 2-round LDS butterfly (w^4 ships ct-half, w^8 ships it-half).
// ---------------------------------------------------------------------------
struct Stage { short8_t k0, k1, v00, v01, v10, v11; };

__global__ __launch_bounds__(1024, 4) void attn_kernel(
    const unsigned short* __restrict__ qfrag,
    const unsigned short* __restrict__ kfrag,
    const unsigned short* __restrict__ vfrag,
    const float* __restrict__ x,             // [B][C][N] fp32
    const float* __restrict__ gamma,
    float* __restrict__ out)
{
    __shared__ float comb[16 * 64 * 9];      // 36.9 KB, end-combine only

    const int m8 = blockIdx.x & 7;
    const int b  = m8 >> 1;
    const int itile = ((blockIdx.x >> 3) << 1) | (m8 & 1);   // 0..63
    const int i0 = itile << 6;
    const int t  = threadIdx.x;
    const int w = t >> 6, lane = t & 63, il = lane & 31, h = lane >> 5;
    const int ci = w & 3, jj = w >> 2;       // jj in 0..3
    const int cbase = ci * 64;

    // Q fragments: chunk (nt = itile*2+it, slot = ks*2+h, il)
    short8_t qf[2][2];
    #pragma unroll
    for (int it = 0; it < 2; ++it)
        #pragma unroll
        for (int ks = 0; ks < 2; ++ks)
            qf[it][ks] = *(const short8_t*)(qfrag +
                (((size_t)(b * 128 + itile * 2 + it) * 4 + ks * 2 + h) * 32 + il) * 8);

    const size_t kbase = (size_t)(b * 128 + jj * 32) * 1024 + h * 256 + il * 8;
    const size_t vbase = (size_t)(b * 128 + jj * 32) * 8192 + h * 2048 + (cbase + il) * 8;

    f32x16 zf;
    #pragma unroll
    for (int r = 0; r < 16; ++r) zf[r] = 0.f;
    f32x16 acc[2][2];    // [it][ct]
    #pragma unroll
    for (int a = 0; a < 2; ++a)
        #pragma unroll
        for (int c2 = 0; c2 < 2; ++c2) acc[a][c2] = zf;
    float ls[2][2] = {{0.f, 0.f}, {0.f, 0.f}};

    Stage A, B;
    auto load = [&](Stage& S, int jt) {
        const unsigned short* kp = kfrag + kbase + (size_t)jt * 1024;
        S.k0  = *(const short8_t*)kp;
        S.k1  = *(const short8_t*)(kp + 512);
        const unsigned short* vp = vfrag + vbase + (size_t)jt * 8192;
        S.v00 = *(const short8_t*)vp;            // ct0, kp0
        S.v01 = *(const short8_t*)(vp + 4096);   // ct0, kp1
        S.v10 = *(const short8_t*)(vp + 256);    // ct1, kp0
        S.v11 = *(const short8_t*)(vp + 4352);   // ct1, kp1
    };
    auto compute = [&](const Stage& S) {
        f32x16 s0 = MFMA32(S.k0, qf[0][0], zf);
        s0 = MFMA32(S.k1, qf[0][1], s0);
        f32x16 s1 = MFMA32(S.k0, qf[1][0], zf);
        s1 = MFMA32(S.k1, qf[1][1], s1);
        unsigned int bf0[2][4], bf1[2][4];
        make_bfrag(s0, ls[0][0], ls[0][1], bf0);
        make_bfrag(s1, ls[1][0], ls[1][1], bf1);
        acc[0][0] = MFMA32(S.v00, u4_to_s8(bf0[0]), acc[0][0]);
        acc[0][0] = MFMA32(S.v01, u4_to_s8(bf0[1]), acc[0][0]);
        acc[0][1] = MFMA32(S.v10, u4_to_s8(bf0[0]), acc[0][1]);
        acc[0][1] = MFMA32(S.v11, u4_to_s8(bf0[1]), acc[0][1]);
        acc[1][0] = MFMA32(S.v00, u4_to_s8(bf1[0]), acc[1][0]);
        acc[1][0] = MFMA32(S.v01, u4_to_s8(bf1[1]), acc[1][0]);
        acc[1][1] = MFMA32(S.v10, u4_to_s8(bf1[0]), acc[1][1]);
        acc[1][1] = MFMA32(S.v11, u4_to_s8(bf1[1]), acc[1][1]);
    };

    load(A, 0);
    load(B, 1);
    for (int jt = 0; jt < 32; jt += 2) {
        compute(A);
        if (jt + 2 < 32) load(A, jt + 2);
        compute(B);
        if (jt + 3 < 32) load(B, jt + 3);
    }

    // ---- end combine over jj quarters ----
    float lv[2];
    #pragma unroll
    for (int it = 0; it < 2; ++it) {
        lv[it] = ls[it][0] + ls[it][1];
        lv[it] += __shfl_xor(lv[it], 32);    // combine h halves of j rows
    }

    const int ctk = jj & 1;                  // ct kept after round 1
    const int itk = jj >> 1;                 // it kept after round 2
    const int my = (w * 64 + lane) * 9;

    // Round 1 (partner w^4, jj LSB): ship acc[it][ctk^1], keep acc[it][ctk]
    #pragma unroll
    for (int it = 0; it < 2; ++it) {
        f32x16& ship = acc[it][ctk ^ 1];
        f32x16& keep = acc[it][ctk];
        #pragma unroll
        for (int half = 0; half < 2; ++half) {
            __syncthreads();
            #pragma unroll
            for (int r = 0; r < 8; ++r)
                comb[my + r] = ship[half * 8 + r];
            if (half == 0) comb[my + 8] = lv[it];
            __syncthreads();
            const int pb = ((w ^ 4) * 64 + lane) * 9;
            #pragma unroll
            for (int r = 0; r < 8; ++r)
                keep[half * 8 + r] += comb[pb + r];
            if (half == 0) lv[it] += comb[pb + 8];
        }
    }

    // Round 2 (partner w^8, jj bit1): ship acc[itk^1][ctk], keep acc[itk][ctk]
    {
        f32x16& ship = acc[itk ^ 1][ctk];
        f32x16& keep = acc[itk][ctk];
        float& lship = lv[itk ^ 1];
        float& lkeep = lv[itk];
        #pragma unroll
        for (int half = 0; half < 2; ++half) {
            __syncthreads();
            #pragma unroll
            for (int r = 0; r < 8; ++r)
                comb[my + r] = ship[half * 8 + r];
            if (half == 0) comb[my + 8] = lship;
            __syncthreads();
            const int pb = ((w ^ 8) * 64 + lane) * 9;
            #pragma unroll
            for (int r = 0; r < 8; ++r)
                keep[half * 8 + r] += comb[pb + r];
            if (half == 0) lkeep += comb[pb + 8];
        }
    }

    // ---- write: wave owns (it = itk, ct = ctk) for its ci ----
    const float sc = gamma[0] / lv[itk];
    const f32x16& oacc = acc[itk][ctk];
    #pragma unroll
    for (int r = 0; r < 16; ++r) {
        const int c = cbase + ctk * 32 + (r & 3) + 8 * (r >> 2) + 4 * h;
        const size_t idx = ((size_t)(b * CCH + c)) * NPIX + i0 + itk * 32 + il;
        out[idx] = x[idx] + oacc[r] * sc;
    }
}

// ---------------------------------------------------------------------------
// Workspace (bf16 elems):
//   wbf[81920] | xfrag[4194304] | qfrag[524288] | kfrag[524288] | vfrag[4194304]
// = 19.1 MB.
// ---------------------------------------------------------------------------
extern "C" void kernel_launch(void* const* d_in, const int* in_sizes, int n_in,
                              void* d_out, int out_size, void* d_ws, size_t ws_size,
                              hipStream_t stream) {
    const float* x     = (const float*)d_in[0];
    const float* Wq    = (const float*)d_in[1];
    const float* bq    = (const float*)d_in[2];
    const float* Wk    = (const float*)d_in[3];
    const float* bk    = (const float*)d_in[4];
    const float* Wv    = (const float*)d_in[5];
    const float* bv    = (const float*)d_in[6];
    const float* gamma = (const float*)d_in[7];
    float* out = (float*)d_out;

    unsigned short* ws    = (unsigned short*)d_ws;
    unsigned short* wbf   = ws;
    unsigned short* xfrag = ws + 81920;
    unsigned short* qfrag = xfrag + (size_t)4194304;
    unsigned short* kfrag = qfrag + (size_t)524288;
    unsigned short* vfrag = kfrag + (size_t)524288;

    prep_kernel<<<dim3(832), dim3(256), 0, stream>>>(Wq, Wk, Wv, x, wbf, xfrag);
    proj_kernel<<<dim3(512), dim3(320), 0, stream>>>(
        xfrag, wbf, bq, bk, bv, qfrag, kfrag, vfrag);
    attn_kernel<<<dim3(256), dim3(1024), 0, stream>>>(
        qfrag, kfrag, vfrag, x, gamma, out);
}